// Round 4
// baseline (204.036 us; speedup 1.0000x reference)
//
#include <hip/hip_runtime.h>

// Problem constants:
//   vol [B=2, C=16, D=96, H=96, W=96] f32
//   xyz_sample [2, 512, 3] f32
//   A [1024, 3, 3] f32
//   weight [6, 1024] f32
//   out [2, 16*512, 1024] f32  (flat: b*8388608 + (c*512+f)*1024 + k)

#define NB 2
#define NC 16
#define NS 96
#define NS3 (NS * NS * NS)
#define FEATS 512
#define NK 1024
#define PASSES 8               // 8 passes x 128 k-slots x 2 duo lanes = 1024 k

#define RVOX 8                 // staged region extent per axis (voxels)

// Swizzled LDS address for (voxel v, half h):
//   v = (zg*8 + yg)*8 + xg, payload 2x16B placed among the voxel's 64B block.
//   slot bits [6:4] of the byte address become {x0, y0^x1, h^z0}; h (duo) is a
//   uniform lane bit, so data-dependent gather reads spread ~evenly over the
//   8 bank slots instead of clustering on x mod 8 (48B-stride layout did).
__device__ __forceinline__ int stage_addr(int xg, int yg, int zg, int h) {
  int v = (zg << 6) + (yg << 3) + xg;
  int sw1 = (yg ^ (xg >> 1)) & 1;
  int sw2 = (h ^ zg) & 1;
  return (v << 6) | (sw1 << 5) | (sw2 << 4);
}

__device__ __forceinline__ unsigned int bfround(float f) {
  unsigned int u = __float_as_uint(f);
  return (u + 0x7fffu + ((u >> 16) & 1u)) >> 16;  // RNE
}

#define BLO(v) __uint_as_float((v) << 16)
#define BHI(v) __uint_as_float((v) & 0xffff0000u)

// ---------------------------------------------------------------------------
// Duo-split trilinear. Each lane owns 8 channels (uint4 = 16B per corner);
// 2 lanes cover a sample. Fast path: LDS-staged 8^3 neighborhood
// (zero-padded => no bounds checks), swizzled addresses. Slow path (~never):
// direct f32 gather from the original [B,C,D,H,W] volume.
// ---------------------------------------------------------------------------
__device__ __forceinline__ void tri_duo(
    const float* __restrict__ vol, size_t cbase,   // vol + (b, duo*8) base
    const unsigned char* __restrict__ stage, int duo,
    int ox0, int oy0, int oz0,
    float x, float y, float z, float sgn, float acc[8]) {
  float fx0 = floorf(x), fy0 = floorf(y), fz0 = floorf(z);
  int ix0 = (int)fx0, iy0 = (int)fy0, iz0 = (int)fz0;
  float tx = x - fx0, ty = y - fy0, tz = z - fz0;
  float wxa[2] = {1.0f - tx, tx};
  float wya[2] = {1.0f - ty, ty};
  float wza[2] = {1.0f - tz, tz};

  int lx0 = ix0 - ox0, ly0 = iy0 - oy0, lz0 = iz0 - oz0;
  bool fast = ((unsigned)lx0 < 7u) & ((unsigned)ly0 < 7u) & ((unsigned)lz0 < 7u);

  if (__builtin_expect(fast, 1)) {
#pragma unroll
    for (int dz = 0; dz < 2; dz++) {
      float wz = sgn * wza[dz];
      int vz = lz0 + dz;
#pragma unroll
      for (int dy = 0; dy < 2; dy++) {
        float wzy = wz * wya[dy];
        int vy = ly0 + dy;
#pragma unroll
        for (int dx = 0; dx < 2; dx++) {
          float w = wzy * wxa[dx];
          int vx = lx0 + dx;
          uint4 u = *(const uint4*)(stage + stage_addr(vx, vy, vz, duo));
          acc[0] += w * BLO(u.x);
          acc[1] += w * BHI(u.x);
          acc[2] += w * BLO(u.y);
          acc[3] += w * BHI(u.y);
          acc[4] += w * BLO(u.z);
          acc[5] += w * BHI(u.z);
          acc[6] += w * BLO(u.w);
          acc[7] += w * BHI(u.w);
        }
      }
    }
  } else {
#pragma unroll
    for (int dz = 0; dz < 2; dz++) {
      int zc = iz0 + dz;
      if ((unsigned)zc >= (unsigned)NS) continue;
#pragma unroll
      for (int dy = 0; dy < 2; dy++) {
        int yc = iy0 + dy;
        if ((unsigned)yc >= (unsigned)NS) continue;
        float wzy = sgn * wza[dz] * wya[dy];
#pragma unroll
        for (int dx = 0; dx < 2; dx++) {
          int xc = ix0 + dx;
          if ((unsigned)xc >= (unsigned)NS) continue;
          float w = wzy * wxa[dx];
          const float* p = vol + cbase + (((size_t)zc * NS + yc) * NS + xc);
#pragma unroll
          for (int c = 0; c < 8; c++)
            acc[c] += w * p[(size_t)c * NS3];
        }
      }
    }
  }
}

// ---------------------------------------------------------------------------
// Fused sample kernel: one block per (b, f). Stages the 8^3 x 16ch
// neighborhood from the f32 volume (bf16 in-register), swizzled into LDS,
// then 8 passes of 128 k-slots x 2 duo lanes with weight prefetch pipeline.
// ---------------------------------------------------------------------------
__global__ __launch_bounds__(256) void sample_fused(
    const float* __restrict__ vol, const float* __restrict__ xyz,
    const float* __restrict__ A, const float* __restrict__ weight,
    float* __restrict__ out) {
  __shared__ __align__(128) unsigned char stage[RVOX * RVOX * RVOX * 64];  // 32 KB

  int n = blockIdx.x;                   // b*512 + f
  int b = n >> 9;
  int f = n & 511;
  int tid = threadIdx.x;

  const float* Xn = xyz + (size_t)n * 3;
  float bx = (Xn[0] + 1.0f) * 48.0f - 0.5f;  // W axis <- xs[0]
  float by = (Xn[1] + 1.0f) * 48.0f - 0.5f;  // H axis <- xs[1]
  float bz = (Xn[2] + 1.0f) * 48.0f - 0.5f;  // D axis <- xs[2]
  int ox0 = (int)floorf(bx) - 3;
  int oy0 = (int)floorf(by) - 3;
  int oz0 = (int)floorf(bz) - 3;

  int duo = tid & 1;                    // which 8-channel half
  int ksub = tid >> 1;                  // 0..127

  const float* An = A + (size_t)n * 9;
  float a00 = An[0], a01 = An[1], a02 = An[2];
  float a10 = An[3], a11 = An[4], a12 = An[5];
  float a20 = An[6], a21 = An[7], a22 = An[8];

  // Stage 512 voxels x 16ch as bf16, zero-filling volume-OOB voxels.
  size_t vb = (size_t)b * NC * NS3;
#pragma unroll
  for (int j = 0; j < 4; j++) {
    int w = tid + 256 * j;              // 0..1023
    int half = w & 1;
    int v = w >> 1;                     // voxel 0..511
    int xg = v & 7, yg = (v >> 3) & 7, zg = v >> 6;
    int xc = ox0 + xg, yc = oy0 + yg, zc = oz0 + zg;
    uint4 r = make_uint4(0u, 0u, 0u, 0u);
    if (((unsigned)xc < (unsigned)NS) & ((unsigned)yc < (unsigned)NS) &
        ((unsigned)zc < (unsigned)NS)) {
      const float* p = vol + vb + (size_t)(half * 8) * NS3 +
                       (((size_t)zc * NS + yc) * NS + xc);
      float f0 = p[0];
      float f1 = p[NS3];
      float f2 = p[2 * NS3];
      float f3 = p[3 * NS3];
      float f4 = p[4 * NS3];
      float f5 = p[5 * NS3];
      float f6 = p[6 * NS3];
      float f7 = p[7 * NS3];
      r.x = bfround(f0) | (bfround(f1) << 16);
      r.y = bfround(f2) | (bfround(f3) << 16);
      r.z = bfround(f4) | (bfround(f5) << 16);
      r.w = bfround(f6) | (bfround(f7) << 16);
    }
    *(uint4*)(stage + stage_addr(xg, yg, zg, half)) = r;
  }
  __syncthreads();

  size_t cbase = ((size_t)b * NC + duo * 8) * NS3;
  size_t obase = (size_t)b * (NC * FEATS * NK) +
                 (size_t)(duo * 8) * (FEATS * NK) + (size_t)f * NK;

  // Weight prefetch pipeline: wc = current pass, wn = next pass.
  float wc[6], wn[6];
#pragma unroll
  for (int q = 0; q < 6; q++) wc[q] = weight[q * NK + ksub];

  for (int pass = 0; pass < PASSES; pass++) {
    int kl = pass * 128 + ksub;
    if (pass < PASSES - 1) {
#pragma unroll
      for (int q = 0; q < 6; q++) wn[q] = weight[q * NK + kl + 128];
    }

    float acc[8] = {0.0f, 0.0f, 0.0f, 0.0f, 0.0f, 0.0f, 0.0f, 0.0f};

    {  // grid 1 (+)
      float oz = a00 * wc[0] + a01 * wc[1] + a02 * wc[2];
      float oy = a10 * wc[0] + a11 * wc[1] + a12 * wc[2];
      float ox = a20 * wc[0] + a21 * wc[1] + a22 * wc[2];
      tri_duo(vol, cbase, stage, duo, ox0, oy0, oz0, bx + ox * 48.0f,
              by + oy * 48.0f, bz + oz * 48.0f, 1.0f, acc);
    }
    {  // grid 2 (-)
      float oz = a00 * wc[3] + a01 * wc[4] + a02 * wc[5];
      float oy = a10 * wc[3] + a11 * wc[4] + a12 * wc[5];
      float ox = a20 * wc[3] + a21 * wc[4] + a22 * wc[5];
      tri_duo(vol, cbase, stage, duo, ox0, oy0, oz0, bx + ox * 48.0f,
              by + oy * 48.0f, bz + oz * 48.0f, -1.0f, acc);
    }

    size_t o = obase + kl;
#pragma unroll
    for (int c = 0; c < 8; c++)
      out[o + (size_t)c * (FEATS * NK)] = acc[c];

#pragma unroll
    for (int q = 0; q < 6; q++) wc[q] = wn[q];
  }
}

extern "C" void kernel_launch(void* const* d_in, const int* in_sizes, int n_in,
                              void* d_out, int out_size, void* d_ws,
                              size_t ws_size, hipStream_t stream) {
  const float* vol    = (const float*)d_in[0];
  const float* xyz    = (const float*)d_in[1];
  const float* A      = (const float*)d_in[2];
  const float* weight = (const float*)d_in[3];
  float* out = (float*)d_out;

  sample_fused<<<NB * FEATS, 256, 0, stream>>>(vol, xyz, A, weight, out);
}

// Round 5
// 201.741 us; speedup vs baseline: 1.0114x; 1.0114x over previous
//
#include <hip/hip_runtime.h>

// Problem constants:
//   vol [B=2, C=16, D=96, H=96, W=96] f32
//   xyz_sample [2, 512, 3] f32
//   A [1024, 3, 3] f32
//   weight [6, 1024] f32
//   out [2, 16*512, 1024] f32  (flat: b*8388608 + (c*512+f)*1024 + k)

#define NB 2
#define NC 16
#define NS 96
#define NS3 (NS * NS * NS)
#define FEATS 512
#define NK 1024
#define KSPLIT 2
#define KCHUNK (NK / KSPLIT)   // 512
#define PASSES 4               // 4 passes x 128 k-slots x 2 duo lanes = 512 k

#define RVOX 8                 // staged region extent per axis (voxels)

// Swizzled LDS address for (voxel, half): 32 B/voxel, 16 KB total.
//   v = zg*64 + yg*8 + xg; addr = ((v ^ ((yg&1)<<1)) << 5) | (((h^zg)&1) << 4)
//   b128 slot bits (addr[6:4]) = {x1^y0, x0, h^z0}: h is a uniform lane bit,
//   x0 spreads with the dx loop, x1^y0 is ~Bernoulli across lanes -> gather
//   reads spread over the 8 bank slots. Bijective for fixed (yg,zg).
__device__ __forceinline__ int stage_addr(int xg, int yg, int zg, int h) {
  int v = (zg << 6) + (yg << 3) + xg;
  v ^= (yg & 1) << 1;
  return (v << 5) | (((h ^ zg) & 1) << 4);
}

__device__ __forceinline__ unsigned int bfround(float f) {
  unsigned int u = __float_as_uint(f);
  return (u + 0x7fffu + ((u >> 16) & 1u)) >> 16;  // RNE
}

#define BLO(v) __uint_as_float((v) << 16)
#define BHI(v) __uint_as_float((v) & 0xffff0000u)

// ---------------------------------------------------------------------------
// Duo-split trilinear. Each lane owns 8 channels (uint4 = 16B per corner);
// 2 lanes cover a sample. Fast path: LDS-staged 8^3 neighborhood
// (zero-padded => no bounds checks), swizzled addresses. Slow path (~never):
// direct f32 gather from the original [B,C,D,H,W] volume.
// ---------------------------------------------------------------------------
__device__ __forceinline__ void tri_duo(
    const float* __restrict__ vol, size_t cbase,   // vol + (b, duo*8) base
    const unsigned char* __restrict__ stage, int duo,
    int ox0, int oy0, int oz0,
    float x, float y, float z, float sgn, float acc[8]) {
  float fx0 = floorf(x), fy0 = floorf(y), fz0 = floorf(z);
  int ix0 = (int)fx0, iy0 = (int)fy0, iz0 = (int)fz0;
  float tx = x - fx0, ty = y - fy0, tz = z - fz0;
  float wxa[2] = {1.0f - tx, tx};
  float wya[2] = {1.0f - ty, ty};
  float wza[2] = {1.0f - tz, tz};

  int lx0 = ix0 - ox0, ly0 = iy0 - oy0, lz0 = iz0 - oz0;
  bool fast = ((unsigned)lx0 < 7u) & ((unsigned)ly0 < 7u) & ((unsigned)lz0 < 7u);

  if (__builtin_expect(fast, 1)) {
#pragma unroll
    for (int dz = 0; dz < 2; dz++) {
      float wz = sgn * wza[dz];
      int vz = lz0 + dz;
#pragma unroll
      for (int dy = 0; dy < 2; dy++) {
        float wzy = wz * wya[dy];
        int vy = ly0 + dy;
#pragma unroll
        for (int dx = 0; dx < 2; dx++) {
          float w = wzy * wxa[dx];
          int vx = lx0 + dx;
          uint4 u = *(const uint4*)(stage + stage_addr(vx, vy, vz, duo));
          acc[0] += w * BLO(u.x);
          acc[1] += w * BHI(u.x);
          acc[2] += w * BLO(u.y);
          acc[3] += w * BHI(u.y);
          acc[4] += w * BLO(u.z);
          acc[5] += w * BHI(u.z);
          acc[6] += w * BLO(u.w);
          acc[7] += w * BHI(u.w);
        }
      }
    }
  } else {
#pragma unroll
    for (int dz = 0; dz < 2; dz++) {
      int zc = iz0 + dz;
      if ((unsigned)zc >= (unsigned)NS) continue;
#pragma unroll
      for (int dy = 0; dy < 2; dy++) {
        int yc = iy0 + dy;
        if ((unsigned)yc >= (unsigned)NS) continue;
        float wzy = sgn * wza[dz] * wya[dy];
#pragma unroll
        for (int dx = 0; dx < 2; dx++) {
          int xc = ix0 + dx;
          if ((unsigned)xc >= (unsigned)NS) continue;
          float w = wzy * wxa[dx];
          const float* p = vol + cbase + (((size_t)zc * NS + yc) * NS + xc);
#pragma unroll
          for (int c = 0; c < 8; c++)
            acc[c] += w * p[(size_t)c * NS3];
        }
      }
    }
  }
}

// ---------------------------------------------------------------------------
// Fused sample kernel: one block per (b, f, kseg). Stages the 8^3 x 16ch
// neighborhood from the f32 volume (bf16 in-register), swizzled into 16 KB
// of LDS, then 4 passes of 128 k-slots x 2 duo lanes with weight prefetch.
// 2048 blocks -> 8 blocks/CU; LDS cap 10, VGPR cap 8 waves/SIMD -> 100% occ.
// ---------------------------------------------------------------------------
__global__ __launch_bounds__(256) void sample_fused(
    const float* __restrict__ vol, const float* __restrict__ xyz,
    const float* __restrict__ A, const float* __restrict__ weight,
    float* __restrict__ out) {
  __shared__ __align__(128) unsigned char stage[RVOX * RVOX * RVOX * 32];  // 16 KB

  int bid = blockIdx.x;
  int kseg = bid & (KSPLIT - 1);
  int n = bid >> 1;                     // b*512 + f
  int b = n >> 9;
  int f = n & 511;
  int kbase = kseg * KCHUNK;
  int tid = threadIdx.x;

  const float* Xn = xyz + (size_t)n * 3;
  float bx = (Xn[0] + 1.0f) * 48.0f - 0.5f;  // W axis <- xs[0]
  float by = (Xn[1] + 1.0f) * 48.0f - 0.5f;  // H axis <- xs[1]
  float bz = (Xn[2] + 1.0f) * 48.0f - 0.5f;  // D axis <- xs[2]
  int ox0 = (int)floorf(bx) - 3;
  int oy0 = (int)floorf(by) - 3;
  int oz0 = (int)floorf(bz) - 3;

  int duo = tid & 1;                    // which 8-channel half
  int ksub = tid >> 1;                  // 0..127

  const float* An = A + (size_t)n * 9;
  float a00 = An[0], a01 = An[1], a02 = An[2];
  float a10 = An[3], a11 = An[4], a12 = An[5];
  float a20 = An[6], a21 = An[7], a22 = An[8];

  // Stage 512 voxels x 16ch as bf16, zero-filling volume-OOB voxels.
  size_t vb = (size_t)b * NC * NS3;
#pragma unroll
  for (int j = 0; j < 4; j++) {
    int w = tid + 256 * j;              // 0..1023
    int half = w & 1;
    int v = w >> 1;                     // voxel 0..511
    int xg = v & 7, yg = (v >> 3) & 7, zg = v >> 6;
    int xc = ox0 + xg, yc = oy0 + yg, zc = oz0 + zg;
    uint4 r = make_uint4(0u, 0u, 0u, 0u);
    if (((unsigned)xc < (unsigned)NS) & ((unsigned)yc < (unsigned)NS) &
        ((unsigned)zc < (unsigned)NS)) {
      const float* p = vol + vb + (size_t)(half * 8) * NS3 +
                       (((size_t)zc * NS + yc) * NS + xc);
      float f0 = p[0];
      float f1 = p[NS3];
      float f2 = p[2 * NS3];
      float f3 = p[3 * NS3];
      float f4 = p[4 * NS3];
      float f5 = p[5 * NS3];
      float f6 = p[6 * NS3];
      float f7 = p[7 * NS3];
      r.x = bfround(f0) | (bfround(f1) << 16);
      r.y = bfround(f2) | (bfround(f3) << 16);
      r.z = bfround(f4) | (bfround(f5) << 16);
      r.w = bfround(f6) | (bfround(f7) << 16);
    }
    *(uint4*)(stage + stage_addr(xg, yg, zg, half)) = r;
  }
  __syncthreads();

  size_t cbase = ((size_t)b * NC + duo * 8) * NS3;
  size_t obase = (size_t)b * (NC * FEATS * NK) +
                 (size_t)(duo * 8) * (FEATS * NK) + (size_t)f * NK + kbase;

  // Weight prefetch pipeline: wc = current pass, wn = next pass.
  float wc[6], wn[6];
#pragma unroll
  for (int q = 0; q < 6; q++) wc[q] = weight[q * NK + kbase + ksub];

  for (int pass = 0; pass < PASSES; pass++) {
    int kl = pass * 128 + ksub;
    if (pass < PASSES - 1) {
#pragma unroll
      for (int q = 0; q < 6; q++) wn[q] = weight[q * NK + kbase + kl + 128];
    }

    float acc[8] = {0.0f, 0.0f, 0.0f, 0.0f, 0.0f, 0.0f, 0.0f, 0.0f};

    {  // grid 1 (+)
      float oz = a00 * wc[0] + a01 * wc[1] + a02 * wc[2];
      float oy = a10 * wc[0] + a11 * wc[1] + a12 * wc[2];
      float ox = a20 * wc[0] + a21 * wc[1] + a22 * wc[2];
      tri_duo(vol, cbase, stage, duo, ox0, oy0, oz0, bx + ox * 48.0f,
              by + oy * 48.0f, bz + oz * 48.0f, 1.0f, acc);
    }
    {  // grid 2 (-)
      float oz = a00 * wc[3] + a01 * wc[4] + a02 * wc[5];
      float oy = a10 * wc[3] + a11 * wc[4] + a12 * wc[5];
      float ox = a20 * wc[3] + a21 * wc[4] + a22 * wc[5];
      tri_duo(vol, cbase, stage, duo, ox0, oy0, oz0, bx + ox * 48.0f,
              by + oy * 48.0f, bz + oz * 48.0f, -1.0f, acc);
    }

    size_t o = obase + kl;
#pragma unroll
    for (int c = 0; c < 8; c++)
      out[o + (size_t)c * (FEATS * NK)] = acc[c];

#pragma unroll
    for (int q = 0; q < 6; q++) wc[q] = wn[q];
  }
}

extern "C" void kernel_launch(void* const* d_in, const int* in_sizes, int n_in,
                              void* d_out, int out_size, void* d_ws,
                              size_t ws_size, hipStream_t stream) {
  const float* vol    = (const float*)d_in[0];
  const float* xyz    = (const float*)d_in[1];
  const float* A      = (const float*)d_in[2];
  const float* weight = (const float*)d_in[3];
  float* out = (float*)d_out;

  sample_fused<<<NB * FEATS * KSPLIT, 256, 0, stream>>>(vol, xyz, A, weight,
                                                        out);
}